// Round 5
// baseline (3688.845 us; speedup 1.0000x reference)
//
#include <hip/hip_runtime.h>

#define N 320
#define D 64

// ---------------------------------------------------------------------------
// Kernel 1: 16 lanes per (i,j) pair, float4 per lane (d = sub*4 .. sub*4+3).
// Computes k, k_xj, k_xi, tr_k_xj_xi, v_t_...; stages sq and Gram G (tiny).
// ---------------------------------------------------------------------------
__global__ __launch_bounds__(256) void pair_kernel(
    const float* __restrict__ x, const float* __restrict__ sigma,
    const float* __restrict__ score, const float* __restrict__ v,
    const float* __restrict__ gvs,
    float* __restrict__ out_k, float* __restrict__ out_kxj,
    float* __restrict__ out_kxi, float* __restrict__ out_tr,
    float* __restrict__ out_vt,
    float* __restrict__ wsSQ, float* __restrict__ wsG)
{
    int tid = threadIdx.x;
    int sub = tid & 15;                       // d-quad index
    int p = blockIdx.x * 16 + (tid >> 4);     // pair index, < N*N
    int i = p / N;
    int j = p - i * N;

    float sg = sigma[0];
    float gamma = 1.0f / (sg * sg + 1e-8f);

    float4 xi4 = *(const float4*)(x     + i * D + sub * 4);
    float4 xj4 = *(const float4*)(x     + j * D + sub * 4);
    float4 sj4 = *(const float4*)(score + j * D + sub * 4);
    float4 vi4 = *(const float4*)(v     + i * D + sub * 4);
    float4 gi4 = *(const float4*)(gvs   + i * D + sub * 4);
    const float* xi = (const float*)&xi4;
    const float* xj = (const float*)&xj4;
    const float* vi = (const float*)&vi4;
    const float* gi = (const float*)&gi4;

    float4 kxj4, kxi4;
    float* kxjp = (float*)&kxj4;
    float* kxip = (float*)&kxi4;

    float r0 = 0.f, r1 = 0.f, r2 = 0.f, r3 = 0.f, r4 = 0.f, r5 = 0.f, r6 = 0.f;
    #pragma unroll
    for (int c = 0; c < 4; ++c) {
        float od   = xi[c] - xj[c];
        float ods  = od * od;
        float gods = gamma * ods;
        float kd   = __expf(-0.5f * gods);
        float kxj  = gamma * kd * od * (1.0f / D);
        kxjp[c] = kxj;
        kxip[c] = -kxj;
        r0 += kd;
        r1 += gamma * (1.0f - gods) * kd;
        r2 += ods;
        r3 += vi[c] * od;
        r4 += gi[c] * od;
        r5 += vi[c] * gi[c];
        r6 += xi[c] * xj[c];
    }

    size_t pd = (size_t)p * D + sub * 4;
    *(float4*)(out_kxj + pd) = kxj4;
    *(float4*)(out_kxi + pd) = kxi4;

    #pragma unroll
    for (int off = 8; off > 0; off >>= 1) {
        r0 += __shfl_xor(r0, off, 64);
        r1 += __shfl_xor(r1, off, 64);
        r2 += __shfl_xor(r2, off, 64);
        r3 += __shfl_xor(r3, off, 64);
        r4 += __shfl_xor(r4, off, 64);
        r5 += __shfl_xor(r5, off, 64);
        r6 += __shfl_xor(r6, off, 64);
    }

    if (sub == 0) {
        float kmean = r0 * (1.0f / D);
        out_k[p]  = kmean;
        out_tr[p] = r1 * (1.0f / D);
        wsSQ[p]   = r2;
        wsG[p]    = r6;
        out_vt[p] = (-2.0f * gamma * r3 * r4 + r5) * kmean * 2.0f * gamma;
    }
}

// ---------------------------------------------------------------------------
// Kernel 2: fused N^3 — out5 (GEMM over d, A/k_d computed on the fly) and
// out6 (Gram identity, pure epilogue arithmetic).
// 128x128 tile per block (8x8 per thread) halves LDS bytes/FMA vs 64x64.
// 320 = 2*128 + 64: pad to 3x3 supertiles, clamp loads, guard stores.
// ---------------------------------------------------------------------------
__global__ __launch_bounds__(256, 2) void triple_kernel(
    const float* __restrict__ x, const float* __restrict__ sigma,
    const float* __restrict__ score,
    const float* __restrict__ kmat, const float* __restrict__ wsSQ,
    const float* __restrict__ wsG,
    float* __restrict__ out5, float* __restrict__ out6)
{
    __shared__ float Alds[128 * 64];
    __shared__ float Klds[128 * 64];

    int i   = blockIdx.z;
    int j0  = blockIdx.y * 128;
    int kk0 = blockIdx.x * 128;
    int tid = threadIdx.x;

    float sg = sigma[0];
    float gamma = 1.0f / (sg * sg + 1e-8f);
    float cA = -gamma * gamma * (1.0f / D);   // A = cA*(1-gods)*score*kd*od
    float g2 = 4.0f * gamma * gamma;

    // ---- stage: A-tile rows j0..j0+127, K-tile rows kk0..kk0+127 ----
    int cw = tid & 15, rw = tid >> 4;
    float4 xi4 = *(const float4*)(x + i * D + cw * 4);
    const float* xi = (const float*)&xi4;
    #pragma unroll
    for (int q = 0; q < 8; ++q) {
        int r = rw + 16 * q;
        int jr = j0 + r;  if (jr > N - 1) jr = N - 1;   // clamp (padded rows)
        int kr = kk0 + r; if (kr > N - 1) kr = N - 1;
        float4 xj4 = *(const float4*)(x     + jr * D + cw * 4);
        float4 sj4 = *(const float4*)(score + jr * D + cw * 4);
        float4 xk4 = *(const float4*)(x     + kr * D + cw * 4);
        const float* xj = (const float*)&xj4;
        const float* sj = (const float*)&sj4;
        const float* xk = (const float*)&xk4;
        float4 av, kv;
        float* avp = (float*)&av;
        float* kvp = (float*)&kv;
        #pragma unroll
        for (int c = 0; c < 4; ++c) {
            float odA  = xi[c] - xj[c];
            float odsA = odA * odA;
            float kdA  = __expf(-0.5f * gamma * odsA);
            avp[c] = cA * (1.0f - gamma * odsA) * sj[c] * kdA * odA;
            float odK = xi[c] - xk[c];
            kvp[c] = __expf(-0.5f * gamma * odK * odK);
        }
        int sc = ((cw ^ (r & 7)) << 2);
        *(float4*)&Alds[r * 64 + sc] = av;
        *(float4*)&Klds[r * 64 + sc] = kv;
    }
    __syncthreads();

    // ---- GEMM: 8x8 register tile, K=64 ----
    int tk = tid & 15, tj = tid >> 4;
    float acc[8][8];
    #pragma unroll
    for (int a = 0; a < 8; ++a)
        #pragma unroll
        for (int b = 0; b < 8; ++b) acc[a][b] = 0.0f;

    #pragma unroll
    for (int c = 0; c < 16; ++c) {
        float4 k4[8];
        #pragma unroll
        for (int kki = 0; kki < 8; ++kki) {
            int r = tk + 16 * kki;
            k4[kki] = *(const float4*)&Klds[r * 64 + ((c ^ (r & 7)) << 2)];
        }
        #pragma unroll
        for (int jj = 0; jj < 8; ++jj) {
            int r = tj + 16 * jj;
            float4 a4 = *(const float4*)&Alds[r * 64 + ((c ^ (r & 7)) << 2)];
            #pragma unroll
            for (int kki = 0; kki < 8; ++kki)
                acc[jj][kki] += a4.x * k4[kki].x + a4.y * k4[kki].y
                              + a4.z * k4[kki].z + a4.w * k4[kki].w;
        }
    }

    // ---- epilogue: out5 + fused out6 (Gram identity) ----
    float Gii = wsG[i * N + i];
    float kikv[8], sqikv[8], Gikv[8];
    #pragma unroll
    for (int kki = 0; kki < 8; ++kki) {
        int kk = kk0 + tk + 16 * kki; if (kk > N - 1) kk = N - 1;
        kikv[kki]  = kmat[i * N + kk];
        sqikv[kki] = wsSQ[i * N + kk];
        Gikv[kki]  = wsG[i * N + kk];
    }
    #pragma unroll
    for (int jj = 0; jj < 8; ++jj) {
        int j = j0 + tj + 16 * jj;
        if (j >= N) continue;
        float kij  = kmat[i * N + j];
        float sqij = wsSQ[i * N + j];
        float Gij  = wsG[i * N + j];
        size_t rowbase = ((size_t)i * N + j) * N;
        #pragma unroll
        for (int kki = 0; kki < 8; ++kki) {
            int kk = kk0 + tk + 16 * kki;
            if (kk >= N) continue;
            out5[rowbase + kk] = acc[jj][kki] * (1.0f / D);
            float Gjk = wsG[j * N + kk];
            float dot = Gii - Gij - Gikv[kki] + Gjk;
            float t1 = dot * dot * g2;
            float t2 = -2.0f * gamma * (sqij + sqikv[kki]);
            out6[rowbase + kk] = (t1 + t2 + (float)D) * kij * kikv[kki] * g2;
        }
    }
}

// ---------------------------------------------------------------------------
extern "C" void kernel_launch(void* const* d_in, const int* in_sizes, int n_in,
                              void* d_out, int out_size, void* d_ws, size_t ws_size,
                              hipStream_t stream) {
    const float* x     = (const float*)d_in[0];
    const float* sigma = (const float*)d_in[1];
    const float* score = (const float*)d_in[2];
    const float* v     = (const float*)d_in[3];
    const float* gvs   = (const float*)d_in[4];

    float* out = (float*)d_out;
    float* out_k   = out;                 // [N,N]      102400
    float* out_kxj = out + 102400;        // [N,N,D]    6553600
    float* out_kxi = out + 6656000;       // [N,N,D]    6553600
    float* out_tr  = out + 13209600;      // [N,N]      102400
    float* out5    = out + 13312000;      // [N,N,N]    32768000
    float* out6    = out + 46080000;      // [N,N,N]    32768000
    float* out_vt  = out + 78848000;      // [N,N]      102400

    float* ws   = (float*)d_ws;
    float* wsSQ = ws;                     // [N,N]
    float* wsG  = ws + 102400;            // [N,N]

    pair_kernel<<<dim3(N * N / 16), dim3(256), 0, stream>>>(
        x, sigma, score, v, gvs,
        out_k, out_kxj, out_kxi, out_tr, out_vt, wsSQ, wsG);

    triple_kernel<<<dim3(3, 3, N), dim3(256), 0, stream>>>(
        x, sigma, score, out_k, wsSQ, wsG, out5, out6);
}

// Round 10
// 1343.109 us; speedup vs baseline: 2.7465x; 2.7465x over previous
//
#include <hip/hip_runtime.h>

#define N 320
#define D 64

// ---------------------------------------------------------------------------
// Kernel 1: 16 lanes per (i,j) pair, float4 per lane (d = sub*4 .. sub*4+3).
// Computes k, k_xj, k_xi, tr_k_xj_xi, v_t_...; stages sq and Gram G (tiny).
// ---------------------------------------------------------------------------
__global__ __launch_bounds__(256) void pair_kernel(
    const float* __restrict__ x, const float* __restrict__ sigma,
    const float* __restrict__ score, const float* __restrict__ v,
    const float* __restrict__ gvs,
    float* __restrict__ out_k, float* __restrict__ out_kxj,
    float* __restrict__ out_kxi, float* __restrict__ out_tr,
    float* __restrict__ out_vt,
    float* __restrict__ wsSQ, float* __restrict__ wsG)
{
    int tid = threadIdx.x;
    int sub = tid & 15;                       // d-quad index
    int p = blockIdx.x * 16 + (tid >> 4);     // pair index, < N*N
    int i = p / N;
    int j = p - i * N;

    float sg = sigma[0];
    float gamma = 1.0f / (sg * sg + 1e-8f);

    float4 xi4 = *(const float4*)(x     + i * D + sub * 4);
    float4 xj4 = *(const float4*)(x     + j * D + sub * 4);
    float4 sj4 = *(const float4*)(score + j * D + sub * 4);
    float4 vi4 = *(const float4*)(v     + i * D + sub * 4);
    float4 gi4 = *(const float4*)(gvs   + i * D + sub * 4);
    const float* xi = (const float*)&xi4;
    const float* xj = (const float*)&xj4;
    const float* vi = (const float*)&vi4;
    const float* gi = (const float*)&gi4;

    float4 kxj4, kxi4;
    float* kxjp = (float*)&kxj4;
    float* kxip = (float*)&kxi4;

    float r0 = 0.f, r1 = 0.f, r2 = 0.f, r3 = 0.f, r4 = 0.f, r5 = 0.f, r6 = 0.f;
    #pragma unroll
    for (int c = 0; c < 4; ++c) {
        float od   = xi[c] - xj[c];
        float ods  = od * od;
        float gods = gamma * ods;
        float kd   = __expf(-0.5f * gods);
        float kxj  = gamma * kd * od * (1.0f / D);
        kxjp[c] = kxj;
        kxip[c] = -kxj;
        r0 += kd;
        r1 += gamma * (1.0f - gods) * kd;
        r2 += ods;
        r3 += vi[c] * od;
        r4 += gi[c] * od;
        r5 += vi[c] * gi[c];
        r6 += xi[c] * xj[c];
    }

    size_t pd = (size_t)p * D + sub * 4;
    *(float4*)(out_kxj + pd) = kxj4;
    *(float4*)(out_kxi + pd) = kxi4;

    #pragma unroll
    for (int off = 8; off > 0; off >>= 1) {
        r0 += __shfl_xor(r0, off, 64);
        r1 += __shfl_xor(r1, off, 64);
        r2 += __shfl_xor(r2, off, 64);
        r3 += __shfl_xor(r3, off, 64);
        r4 += __shfl_xor(r4, off, 64);
        r5 += __shfl_xor(r5, off, 64);
        r6 += __shfl_xor(r6, off, 64);
    }

    if (sub == 0) {
        float kmean = r0 * (1.0f / D);
        out_k[p]  = kmean;
        out_tr[p] = r1 * (1.0f / D);
        wsSQ[p]   = r2;
        wsG[p]    = r6;
        out_vt[p] = (-2.0f * gamma * r3 * r4 + r5) * kmean * 2.0f * gamma;
    }
}

// ---------------------------------------------------------------------------
// Kernel 2: fused N^3 — out5 (GEMM over d, A/k_d computed on the fly) and
// out6 (Gram identity epilogue).
// Tile: BM=128 j-rows x BN=64 kk-cols per block, 8x4 per thread (acc = 32
// VGPRs — round-5's 8x8/64-reg acc spilled to scratch: 9 GB HBM, 38x slow).
// BN=64 divides 320 exactly -> no kk guard; only j0=256 tile needs guards.
// ---------------------------------------------------------------------------
__global__ __launch_bounds__(256) void triple_kernel(
    const float* __restrict__ x, const float* __restrict__ sigma,
    const float* __restrict__ score,
    const float* __restrict__ kmat, const float* __restrict__ wsSQ,
    const float* __restrict__ wsG,
    float* __restrict__ out5, float* __restrict__ out6)
{
    __shared__ float Alds[128 * 64];   // 32 KB, rows j0..j0+127
    __shared__ float Klds[64 * 64];    // 16 KB, rows kk0..kk0+63

    int i   = blockIdx.z;
    int j0  = blockIdx.y * 128;
    int kk0 = blockIdx.x * 64;
    int tid = threadIdx.x;

    float sg = sigma[0];
    float gamma = 1.0f / (sg * sg + 1e-8f);
    float cA = -gamma * gamma * (1.0f / D);   // A = cA*(1-gods)*score*kd*od
    float g2 = 4.0f * gamma * gamma;

    int cw = tid & 15, rw = tid >> 4;
    float4 xi4 = *(const float4*)(x + i * D + cw * 4);
    const float* xi = (const float*)&xi4;

    // ---- stage A-tile: 8 rows/thread, clamp rows past N (j0=256 tile) ----
    #pragma unroll
    for (int q = 0; q < 8; ++q) {
        int r = rw + 16 * q;
        int jr = j0 + r;  if (jr > N - 1) jr = N - 1;
        float4 xj4 = *(const float4*)(x     + jr * D + cw * 4);
        float4 sj4 = *(const float4*)(score + jr * D + cw * 4);
        const float* xj = (const float*)&xj4;
        const float* sj = (const float*)&sj4;
        float4 av;
        float* avp = (float*)&av;
        #pragma unroll
        for (int c = 0; c < 4; ++c) {
            float od  = xi[c] - xj[c];
            float ods = od * od;
            float kd  = __expf(-0.5f * gamma * ods);
            avp[c] = cA * (1.0f - gamma * ods) * sj[c] * kd * od;
        }
        *(float4*)&Alds[r * 64 + ((cw ^ (r & 7)) << 2)] = av;
    }
    // ---- stage K-tile: 4 rows/thread, no clamp (5*64 = 320 exact) ----
    #pragma unroll
    for (int q = 0; q < 4; ++q) {
        int r = rw + 16 * q;
        float4 xk4 = *(const float4*)(x + (kk0 + r) * D + cw * 4);
        const float* xk = (const float*)&xk4;
        float4 kv;
        float* kvp = (float*)&kv;
        #pragma unroll
        for (int c = 0; c < 4; ++c) {
            float od = xi[c] - xk[c];
            kvp[c] = __expf(-0.5f * gamma * od * od);
        }
        *(float4*)&Klds[r * 64 + ((cw ^ (r & 7)) << 2)] = kv;
    }
    __syncthreads();

    // ---- GEMM: 8x4 register tile, K=64 ----
    int tk = tid & 15, tj = tid >> 4;
    float acc[8][4];
    #pragma unroll
    for (int a = 0; a < 8; ++a)
        #pragma unroll
        for (int b = 0; b < 4; ++b) acc[a][b] = 0.0f;

    #pragma unroll
    for (int c = 0; c < 16; ++c) {
        float4 k4[4];
        #pragma unroll
        for (int kki = 0; kki < 4; ++kki) {
            int r = tk + 16 * kki;
            k4[kki] = *(const float4*)&Klds[r * 64 + ((c ^ (r & 7)) << 2)];
        }
        #pragma unroll
        for (int jj = 0; jj < 8; ++jj) {
            int r = tj + 16 * jj;
            float4 a4 = *(const float4*)&Alds[r * 64 + ((c ^ (r & 7)) << 2)];
            #pragma unroll
            for (int kki = 0; kki < 4; ++kki)
                acc[jj][kki] += a4.x * k4[kki].x + a4.y * k4[kki].y
                              + a4.z * k4[kki].z + a4.w * k4[kki].w;
        }
    }

    // ---- epilogue: out5 + fused out6 (Gram identity) ----
    float Gii = wsG[i * N + i];
    float kikv[4], sqikv[4], Gikv[4];
    #pragma unroll
    for (int kki = 0; kki < 4; ++kki) {
        int kk = kk0 + tk + 16 * kki;          // always < N
        kikv[kki]  = kmat[i * N + kk];
        sqikv[kki] = wsSQ[i * N + kk];
        Gikv[kki]  = wsG[i * N + kk];
    }
    #pragma unroll
    for (int jj = 0; jj < 8; ++jj) {
        int j = j0 + tj + 16 * jj;
        if (j >= N) continue;
        float kij  = kmat[i * N + j];
        float sqij = wsSQ[i * N + j];
        float Gij  = wsG[i * N + j];
        size_t rowbase = ((size_t)i * N + j) * N;
        #pragma unroll
        for (int kki = 0; kki < 4; ++kki) {
            int kk = kk0 + tk + 16 * kki;
            out5[rowbase + kk] = acc[jj][kki] * (1.0f / D);
            float Gjk = wsG[j * N + kk];
            float dot = Gii - Gij - Gikv[kki] + Gjk;
            float t1 = dot * dot * g2;
            float t2 = -2.0f * gamma * (sqij + sqikv[kki]);
            out6[rowbase + kk] = (t1 + t2 + (float)D) * kij * kikv[kki] * g2;
        }
    }
}

// ---------------------------------------------------------------------------
extern "C" void kernel_launch(void* const* d_in, const int* in_sizes, int n_in,
                              void* d_out, int out_size, void* d_ws, size_t ws_size,
                              hipStream_t stream) {
    const float* x     = (const float*)d_in[0];
    const float* sigma = (const float*)d_in[1];
    const float* score = (const float*)d_in[2];
    const float* v     = (const float*)d_in[3];
    const float* gvs   = (const float*)d_in[4];

    float* out = (float*)d_out;
    float* out_k   = out;                 // [N,N]      102400
    float* out_kxj = out + 102400;        // [N,N,D]    6553600
    float* out_kxi = out + 6656000;       // [N,N,D]    6553600
    float* out_tr  = out + 13209600;      // [N,N]      102400
    float* out5    = out + 13312000;      // [N,N,N]    32768000
    float* out6    = out + 46080000;      // [N,N,N]    32768000
    float* out_vt  = out + 78848000;      // [N,N]      102400

    float* ws   = (float*)d_ws;
    float* wsSQ = ws;                     // [N,N]
    float* wsG  = ws + 102400;            // [N,N]

    pair_kernel<<<dim3(N * N / 16), dim3(256), 0, stream>>>(
        x, sigma, score, v, gvs,
        out_k, out_kxj, out_kxi, out_tr, out_vt, wsSQ, wsG);

    triple_kernel<<<dim3(5, 3, N), dim3(256), 0, stream>>>(
        x, sigma, score, out_k, wsSQ, wsG, out5, out6);
}